// Round 2
// baseline (11606.539 us; speedup 1.0000x reference)
//
#include <hip/hip_runtime.h>

// Delayed-feedback LSTM, persistent kernel: 256 WGs (1 batch elem / CU), 512 thr.
// Serial phase: W_hh matvec with 8 gates/thread, k-split x4 (kq = tid>>7),
//   weights 30 f16-pairs/gate in VGPRs + 2 pairs/gate in LDS (32 KB).
// Gate rows permuted g' = unit*4 + type for contiguous partial reduction.
// Chunk phase (CH=8): x|fb gate GEMM via MFMA 16x16x32_f16, B pre-packed in ws.
// Output matvec per chunk from a global h-history ring (latency tolerant).

#define BATCH   256
#define TSTEPS  1024
#define IN_DIM  64
#define HID     256
#define G4      1024
#define OUT_DIM 64
#define DELAY   20
#define CH      8
#define NCH     (TSTEPS / CH)
#define NTHR    512
#define WREGP   30              // f16 pairs per gate in registers
#define SMEM_BYTES 65280

typedef unsigned int u32;
typedef _Float16 half2_t __attribute__((ext_vector_type(2)));
typedef _Float16 v8h     __attribute__((ext_vector_type(8)));
typedef float    v4f     __attribute__((ext_vector_type(4)));

union H2U { u32 u; half2_t h; };
union H1U { unsigned short s; _Float16 h; };
union U4H { uint4 u; v8h h; };

__device__ __forceinline__ u32 pack2(float a, float b) {
    H2U x; x.h = half2_t{(_Float16)a, (_Float16)b}; return x.u;
}
__device__ __forceinline__ unsigned short f16bits(float a) {
    H1U x; x.h = (_Float16)a; return x.s;
}
__device__ __forceinline__ float lo16(u32 u) {
    H1U x; x.s = (unsigned short)(u & 0xffffu); return (float)x.h;
}
__device__ __forceinline__ float hi16(u32 u) {
    H1U x; x.s = (unsigned short)(u >> 16); return (float)x.h;
}
__device__ __forceinline__ float dot2(u32 w, u32 h, float acc) {
    H2U a; a.u = w; H2U b; b.u = h;
    return __builtin_amdgcn_fdot2(a.h, b.h, acc, false);
}
__device__ __forceinline__ float sigm(float x) {
    float e = __expf(-fabsf(x));
    float p = 1.f / (1.f + e);
    return x >= 0.f ? p : 1.f - p;
}
__device__ __forceinline__ float tanh_f(float x) {
    float e = __expf(-2.f * fabsf(x));
    float r = (1.f - e) / (1.f + e);
    return x >= 0.f ? r : -r;
}

// LDS layout (bytes), total 65280 <= 65536 (no attribute needed)
#define OFF_LDSW  0        // u32 [512 thr][16]          32768
#define OFF_CB    32768    // ushort [8][1024]           16384
#define OFF_PART  49152    // ushort [4][1024]            8192
#define OFF_HH    57344    // ushort [2][256]             1024
#define OFF_RING  58368    // ushort [20][64]             2560
#define OFF_XF    60928    // u32 [16 rows][68]           4352

// ws layout (bytes)
#define WS_BPK    0                    // 262144: MFMA-B packed Wx|Wfb
#define WS_WOUT   262144               // 32768 : packed Wout
#define WS_HG     294912               // 2097152: h history [256 b][16][256] f16
#define WS_NEED   (294912 + 2097152)

// permuted gate g' = u*4 + ty  ->  original row ty*256 + u
__device__ __forceinline__ int orig_row(int gp) {
    return (gp & 3) * 256 + (gp >> 2);
}

__global__ void prepack(const float* __restrict__ Wx,
                        const float* __restrict__ Wfb,
                        const float* __restrict__ Wout,
                        u32* __restrict__ Bpk, u32* __restrict__ Woutpk)
{
    int id = blockIdx.x * 256 + threadIdx.x;
    if (id < 16384) {
        // B-fragment pack: slot = (nt*4 + kb)*64 + lane ; 8 f16 (k asc) per lane
        int lane = id & 63, kb = (id >> 6) & 3, nt = id >> 8;
        int gp = nt * 16 + (lane & 15);
        int r = orig_row(gp);
        int k0 = kb * 32 + (lane >> 4) * 8;
        u32 v[4];
#pragma unroll
        for (int c = 0; c < 4; ++c) {
            int k = k0 + 2 * c;
            float f0 = (k < 64) ? Wx[r * 64 + k] : Wfb[r * 64 + k - 64];
            float f1 = (k + 1 < 64) ? Wx[r * 64 + k + 1] : Wfb[r * 64 + k + 1 - 64];
            v[c] = pack2(f0, f1);
        }
        ((uint4*)Bpk)[id] = make_uint4(v[0], v[1], v[2], v[3]);
    } else if (id < 16384 + 8192) {
        int s = id - 16384;                 // flat uint idx = (w4*64+o)*4+c
        int c = s & 3, o = (s >> 2) & 63, w4 = s >> 8;
        int kp = w4 * 4 + c;
        Woutpk[s] = pack2(Wout[o * 256 + 2 * kp], Wout[o * 256 + 2 * kp + 1]);
    }
}

__global__ __launch_bounds__(NTHR, 2)
void lstm_persist(const float* __restrict__ input,
                  const float* __restrict__ Whh,
                  const float* __restrict__ bih,
                  const float* __restrict__ bhh,
                  const float* __restrict__ bout_g,
                  const u32* __restrict__ Bpk,
                  const u32* __restrict__ Woutpk,
                  unsigned short* __restrict__ hg_all,
                  float* __restrict__ out)
{
    extern __shared__ char smem[];
    u32*            lds_w = (u32*)(smem + OFF_LDSW);
    unsigned short* cb    = (unsigned short*)(smem + OFF_CB);
    unsigned short* part  = (unsigned short*)(smem + OFF_PART);
    unsigned short* hh    = (unsigned short*)(smem + OFF_HH);
    unsigned short* ring  = (unsigned short*)(smem + OFF_RING);
    u32*            xfst  = (u32*)(smem + OFF_XF);

    const int tid  = threadIdx.x;
    const int b    = blockIdx.x;
    const int kq   = tid >> 7;        // 0..3  (wave-uniform)
    const int gl   = tid & 127;       // gate block: gates gl*8 .. gl*8+7 (permuted)
    const int lane = tid & 63;

    const float* xin  = input + (size_t)b * TSTEPS * IN_DIM;
    float*       outp = out + (size_t)b * TSTEPS * OUT_DIM;
    unsigned short* hg = hg_all + (size_t)b * (16 * HID);
    const float bo_reg = bout_g[tid & 63];

    // ---- init: W_hh k-quarter into regs (30 pairs/gate) + LDS (2 pairs/gate)
    u32 wreg[8][WREGP];
#pragma unroll
    for (int j = 0; j < 8; ++j) {
        const int r = orig_row(gl * 8 + j);
        const float* wrow = Whh + (size_t)r * HID + kq * 64;
#pragma unroll
        for (int p = 0; p < WREGP; ++p) {
            float2 w2 = *(const float2*)(wrow + 2 * p);
            wreg[j][p] = pack2(w2.x, w2.y);
        }
#pragma unroll
        for (int s = 0; s < 2; ++s) {
            float2 w2 = *(const float2*)(wrow + 60 + 2 * s);
            lds_w[tid * 16 + j * 2 + s] = pack2(w2.x, w2.y);
        }
    }
    // zero h ping-pong and MFMA-A padding rows (rows 8..15)
    if (tid < 256) { hh[tid] = 0; hh[256 + tid] = 0; }
    for (int i = tid; i < 8 * 68; i += NTHR) xfst[8 * 68 + i] = 0;
    __syncthreads();

    float c_state = 0.f;

    // out matvec for steps [tbase, tbase+8), from global h-history ring
    auto out_chunk = [&](int tbase) {
        if (tid < 256) {
            const int o = tid & 63, q = tid >> 6;
            const uint4* wp = (const uint4*)Woutpk;
#pragma unroll
            for (int half = 0; half < 2; ++half) {
                int t = tbase + q + 4 * half;
                const uint4* hrow = (const uint4*)(hg + (t & 15) * HID);
                float a = bo_reg;
                for (int w4 = 0; w4 < 32; ++w4) {
                    uint4 wv = wp[w4 * 64 + o];
                    uint4 hv = hrow[w4];
                    a = dot2(wv.x, hv.x, a);
                    a = dot2(wv.y, hv.y, a);
                    a = dot2(wv.z, hv.z, a);
                    a = dot2(wv.w, hv.w, a);
                }
                outp[(size_t)t * OUT_DIM + o] = a;
                ring[(t % 20) * 64 + o] = f16bits(a);
            }
        }
    };

    for (int ch = 0; ch < NCH; ++ch) {
        const int t0 = ch * CH;
        if (ch > 0) out_chunk(t0 - CH);
        __syncthreads();

        // ---- stage x|fb rows (8 rows x 64 uints) as f16 pairs
        {
            int row = tid >> 6, p = tid & 63;
            int t = t0 + row;
            u32 v;
            if (p < 32) {
                float2 x2 = *(const float2*)(xin + (size_t)t * IN_DIM + 2 * p);
                v = pack2(x2.x, x2.y);
            } else {
                int src = t - DELAY;
                if (src >= 0) {
                    int d = 2 * (p - 32);
                    int slot = src % 20;
                    v = (u32)ring[slot * 64 + d] | ((u32)ring[slot * 64 + d + 1] << 16);
                } else v = 0u;
            }
            xfst[row * 68 + p] = v;
        }
        __syncthreads();

        // ---- chunk gate pre-acts via MFMA: cb[tl][g'] = bias + x@Wx^T + fb@Wfb^T
        {
            const int m = lane & 15, quad = lane >> 4;
            uint4 afr[4];
#pragma unroll
            for (int kb = 0; kb < 4; ++kb)
                afr[kb] = *(const uint4*)(xfst + m * 68 + kb * 16 + quad * 4);
            const int w = tid >> 6;
            for (int nt8 = 0; nt8 < 8; ++nt8) {
                const int nt = w + nt8 * 8;
                const int gcol = nt * 16 + m;
                const int r = orig_row(gcol);
                const float bias = bih[r] + bhh[r];
                v4f acc = {0.f, 0.f, 0.f, 0.f};
#pragma unroll
                for (int kb = 0; kb < 4; ++kb) {
                    U4H a; a.u = afr[kb];
                    U4H bb; bb.u = *(const uint4*)(Bpk + (nt * 256 + kb * 64 + lane) * 4);
                    acc = __builtin_amdgcn_mfma_f32_16x16x32_f16(a.h, bb.h, acc, 0, 0, 0);
                }
                if (quad < 2) {
#pragma unroll
                    for (int rg = 0; rg < 4; ++rg) {
                        int row = quad * 4 + rg;
                        cb[row * G4 + gcol] = f16bits(acc[rg] + bias);
                    }
                }
            }
        }
        __syncthreads();

        // ---- 8 serial steps
        for (int tl = 0; tl < CH; ++tl) {
            const int t = t0 + tl;
            const uint4* hrow4 = (const uint4*)((const u32*)hh + ((t + 1) & 1) * 128);

            float acc[8];
            if (kq == 0) {
                uint4 cv = *(const uint4*)(cb + tl * G4 + gl * 8);
                acc[0] = lo16(cv.x); acc[1] = hi16(cv.x);
                acc[2] = lo16(cv.y); acc[3] = hi16(cv.y);
                acc[4] = lo16(cv.z); acc[5] = hi16(cv.z);
                acc[6] = lo16(cv.w); acc[7] = hi16(cv.w);
            } else {
#pragma unroll
                for (int j = 0; j < 8; ++j) acc[j] = 0.f;
            }
#pragma unroll
            for (int w4 = 0; w4 < 7; ++w4) {
                uint4 hv = hrow4[kq * 8 + w4];
#pragma unroll
                for (int j = 0; j < 8; ++j) {
                    acc[j] = dot2(wreg[j][w4 * 4 + 0], hv.x, acc[j]);
                    acc[j] = dot2(wreg[j][w4 * 4 + 1], hv.y, acc[j]);
                    acc[j] = dot2(wreg[j][w4 * 4 + 2], hv.z, acc[j]);
                    acc[j] = dot2(wreg[j][w4 * 4 + 3], hv.w, acc[j]);
                }
            }
            {   // tail: pairs 28,29 (regs) + 30,31 (LDS)
                uint4 hv = hrow4[kq * 8 + 7];
#pragma unroll
                for (int j = 0; j < 8; ++j) {
                    acc[j] = dot2(wreg[j][28], hv.x, acc[j]);
                    acc[j] = dot2(wreg[j][29], hv.y, acc[j]);
                }
#pragma unroll
                for (int m = 0; m < 4; ++m) {
                    uint4 lw = *(const uint4*)(lds_w + tid * 16 + m * 4);
                    acc[2 * m]     = dot2(lw.x, hv.z, acc[2 * m]);
                    acc[2 * m]     = dot2(lw.y, hv.w, acc[2 * m]);
                    acc[2 * m + 1] = dot2(lw.z, hv.z, acc[2 * m + 1]);
                    acc[2 * m + 1] = dot2(lw.w, hv.w, acc[2 * m + 1]);
                }
            }
            // write 8-gate partial (f16x8 = one b128)
            {
                uint4 pw;
                pw.x = pack2(acc[0], acc[1]); pw.y = pack2(acc[2], acc[3]);
                pw.z = pack2(acc[4], acc[5]); pw.w = pack2(acc[6], acc[7]);
                *(uint4*)(part + kq * G4 + gl * 8) = pw;
            }
            __syncthreads();

            if (tid < 256) {
                float s0 = 0.f, s1 = 0.f, s2 = 0.f, s3 = 0.f;
#pragma unroll
                for (int k = 0; k < 4; ++k) {
                    uint2 rd = *(const uint2*)(part + k * G4 + tid * 4);
                    s0 += lo16(rd.x); s1 += hi16(rd.x);
                    s2 += lo16(rd.y); s3 += hi16(rd.y);
                }
                // permuted order: ty 0=i, 1=f, 2=g, 3=o
                c_state = sigm(s1) * c_state + sigm(s0) * tanh_f(s2);
                float hval = sigm(s3) * tanh_f(c_state);
                unsigned short hb = f16bits(hval);
                hh[(t & 1) * HID + tid] = hb;
                hg[(t & 15) * HID + tid] = hb;
            }
            __syncthreads();
        }
    }
    out_chunk(TSTEPS - CH);
}

extern "C" void kernel_launch(void* const* d_in, const int* in_sizes, int n_in,
                              void* d_out, int out_size, void* d_ws, size_t ws_size,
                              hipStream_t stream)
{
    (void)in_sizes; (void)n_in; (void)out_size;
    const float* input = (const float*)d_in[0];
    const float* Wx    = (const float*)d_in[1];
    const float* Wfb   = (const float*)d_in[2];
    const float* Whh   = (const float*)d_in[3];
    const float* bih   = (const float*)d_in[4];
    const float* bhh   = (const float*)d_in[5];
    const float* Wo    = (const float*)d_in[6];
    const float* bog   = (const float*)d_in[7];
    float* out = (float*)d_out;

    if (ws_size < (size_t)WS_NEED) return;  // visible failure, no crash

    u32* Bpk    = (u32*)((char*)d_ws + WS_BPK);
    u32* Woutpk = (u32*)((char*)d_ws + WS_WOUT);
    unsigned short* hg = (unsigned short*)((char*)d_ws + WS_HG);

    prepack<<<dim3(96), dim3(256), 0, stream>>>(Wx, Wfb, Wo, Bpk, Woutpk);
    lstm_persist<<<dim3(BATCH), dim3(NTHR), SMEM_BYTES, stream>>>(
        input, Whh, bih, bhh, bog, Bpk, Woutpk, hg, out);
}

// Round 3
// 7249.800 us; speedup vs baseline: 1.6009x; 1.6009x over previous
//
#include <hip/hip_runtime.h>

// Delayed-feedback LSTM, persistent kernel: 256 WGs (1 batch elem/CU), 512 thr.
// NO MFMA anywhere (MFMA forced a 128/128 arch/accum register split in r2 and
// spilled the weight array to scratch -> 11.6 ms, L3-bound).
// Serial h-matvec: kq = tid>>7 (k-quarter, wave-uniform), 8 gates/thread.
// Per gate (32 f16-pairs per k-quarter): pairs 0..25 in VGPRs (208 regs),
// 26..27 in LDS (32 KB), 28..31 streamed from global (L2-resident, shared
// across all WGs). Gates processed in 2 halves of 4 to cap liveness.
// Chunk phase (CH=8): x|fb gate matvec via dot2, weights streamed once/chunk.

#define BATCH   256
#define TSTEPS  1024
#define IN_DIM  64
#define HID     256
#define G4      1024
#define OUT_DIM 64
#define DELAY   20
#define CH      8
#define NCH     (TSTEPS / CH)
#define NTHR    512
#define REGP    26              // f16 pairs per gate in registers

typedef unsigned int u32;
typedef _Float16 half2_t __attribute__((ext_vector_type(2)));

union H2U { u32 u; half2_t h; };
union H1U { unsigned short s; _Float16 h; };

__device__ __forceinline__ u32 pack2(float a, float b) {
    H2U x; x.h = half2_t{(_Float16)a, (_Float16)b}; return x.u;
}
__device__ __forceinline__ unsigned short f16bits(float a) {
    H1U x; x.h = (_Float16)a; return x.s;
}
__device__ __forceinline__ float lo16(u32 u) {
    H1U x; x.s = (unsigned short)(u & 0xffffu); return (float)x.h;
}
__device__ __forceinline__ float hi16(u32 u) {
    H1U x; x.s = (unsigned short)(u >> 16); return (float)x.h;
}
__device__ __forceinline__ float dot2(u32 w, u32 h, float acc) {
    H2U a; a.u = w; H2U b; b.u = h;
    return __builtin_amdgcn_fdot2(a.h, b.h, acc, false);
}
__device__ __forceinline__ float sigm(float x) {
    float e = __expf(-fabsf(x));
    float p = 1.f / (1.f + e);
    return x >= 0.f ? p : 1.f - p;
}
__device__ __forceinline__ float tanh_f(float x) {
    float e = __expf(-2.f * fabsf(x));
    float r = (1.f - e) / (1.f + e);
    return x >= 0.f ? r : -r;
}

// LDS layout (bytes), total 63104 <= 65536
#define OFF_LDSW  0        // uint2 [8 q][512 tid]      32768
#define OFF_CB    32768    // u32   [8 tl][512]         16384  (2 gates/u32, f16)
#define OFF_PART  49152    // ushort[4 kq][1024]         8192
#define OFF_HH    57344    // ushort[2][256]             1024
#define OFF_RING  58368    // ushort[20][64]             2560
#define OFF_XF    60928    // u32   [8][68]              2176
#define SMEM_BYTES 63104

// ws layout (bytes)
#define WS_BPK    0                    // 262144: chunk Wx|Wfb packed (uint4)
#define WS_WGR    262144               // 65536 : serial W_hh tail (uint4)
#define WS_WOUT   327680               // 32768 : packed Wout (u32)
#define WS_BSUM   360448               // 4096  : bias sums (float, permuted)
#define WS_HG     364544               // 2097152: h history [256 b][16][256] f16
#define WS_NEED   (364544 + 2097152)

// permuted gate g' = u*4 + ty  ->  original row ty*256 + u  (ty: 0=i,1=f,2=g,3=o)
__device__ __forceinline__ int orig_row(int gp) {
    return (gp & 3) * 256 + (gp >> 2);
}

__global__ void prepack(const float* __restrict__ Wx,
                        const float* __restrict__ Wfb,
                        const float* __restrict__ Whh,
                        const float* __restrict__ Wout,
                        const float* __restrict__ bih,
                        const float* __restrict__ bhh,
                        uint4* __restrict__ Bpk4,
                        uint4* __restrict__ WgR4,
                        u32* __restrict__ Woutpk,
                        float* __restrict__ bsum_g)
{
    int id = blockIdx.x * 256 + threadIdx.x;
    if (id < 16384) {
        // Bpk4[(j*16+kb)*512 + t]: gate g'=2t+j, K=128 (x|fb), k = kb*8..kb*8+7
        int t = id & 511, rest = id >> 9;
        int kb = rest & 15, j = rest >> 4;
        int r = orig_row(2 * t + j);
        int k0 = kb * 8;
        const float* src = (k0 < 64) ? (Wx + (size_t)r * 64 + k0)
                                     : (Wfb + (size_t)r * 64 + (k0 - 64));
        uint4 v;
        v.x = pack2(src[0], src[1]); v.y = pack2(src[2], src[3]);
        v.z = pack2(src[4], src[5]); v.w = pack2(src[6], src[7]);
        Bpk4[id] = v;
    } else if (id < 16384 + 4096) {
        // WgR4[q*512 + tid]: gate g'=(tid&127)*8+q, quarter kq=tid>>7, k 56..63
        int s = id - 16384;
        int tt = s & 511, q = s >> 9;
        int kq = tt >> 7, gl = tt & 127;
        int r = orig_row(gl * 8 + q);
        const float* w = Whh + (size_t)r * HID + kq * 64 + 56;
        uint4 v;
        v.x = pack2(w[0], w[1]); v.y = pack2(w[2], w[3]);
        v.z = pack2(w[4], w[5]); v.w = pack2(w[6], w[7]);
        WgR4[s] = v;
    } else if (id < 16384 + 4096 + 8192) {
        int s = id - 20480;                 // (w4*64+o)*4+c
        int c = s & 3, o = (s >> 2) & 63, w4 = s >> 8;
        int kp = w4 * 4 + c;
        Woutpk[s] = pack2(Wout[o * HID + 2 * kp], Wout[o * HID + 2 * kp + 1]);
    } else if (id < 16384 + 4096 + 8192 + 1024) {
        int g = id - 28672;
        int r = orig_row(g);
        bsum_g[g] = bih[r] + bhh[r];
    }
}

__global__ __launch_bounds__(NTHR, 2)
void lstm_persist(const float* __restrict__ input,
                  const float* __restrict__ Whh,
                  const float* __restrict__ bout_g,
                  const uint4* __restrict__ Bpk4,
                  const uint4* __restrict__ WgR4,
                  const u32* __restrict__ Woutpk,
                  const float* __restrict__ bsum_g,
                  unsigned short* __restrict__ hg_all,
                  float* __restrict__ out)
{
    extern __shared__ char smem[];
    u32*            ldsw  = (u32*)(smem + OFF_LDSW);
    u32*            cb32  = (u32*)(smem + OFF_CB);
    unsigned short* part  = (unsigned short*)(smem + OFF_PART);
    unsigned short* hh    = (unsigned short*)(smem + OFF_HH);
    unsigned short* ring  = (unsigned short*)(smem + OFF_RING);
    u32*            xfst  = (u32*)(smem + OFF_XF);

    const int tid = threadIdx.x;
    const int b   = blockIdx.x;
    const int kq  = tid >> 7;         // wave-uniform k-quarter
    const int gl  = tid & 127;        // gate block: permuted gates gl*8..gl*8+7

    const float* xin  = input + (size_t)b * TSTEPS * IN_DIM;
    float*       outp = out + (size_t)b * TSTEPS * OUT_DIM;
    unsigned short* hg = hg_all + (size_t)b * (16 * HID);
    const float bo_reg = bout_g[tid & 63];

    // ---- init: W_hh pairs 0..25 of k-quarter into regs, 26..27 into LDS ----
    u32 wreg[8][REGP];
#pragma unroll
    for (int q = 0; q < 8; ++q) {
        const int r = orig_row(gl * 8 + q);
        const float* wrow = Whh + (size_t)r * HID + kq * 64;
#pragma unroll
        for (int p = 0; p < REGP; ++p) {
            float2 w2 = *(const float2*)(wrow + 2 * p);
            wreg[q][p] = pack2(w2.x, w2.y);
        }
        float2 wa = *(const float2*)(wrow + 52);
        float2 wb = *(const float2*)(wrow + 54);
        u32 base = (q * 512 + tid) * 2;
        ldsw[base]     = pack2(wa.x, wa.y);
        ldsw[base + 1] = pack2(wb.x, wb.y);
    }
    if (tid < 256) { hh[tid] = 0; hh[256 + tid] = 0; }
    __syncthreads();

    float c_state = 0.f;

    // out matvec for steps [tbase, tbase+8): one (t,o) per thread
    auto out_chunk = [&](int tbase) {
        const int lt = tid >> 6, o = tid & 63;
        const int t = tbase + lt;
        const uint4* hrow = (const uint4*)(hg + (t & 15) * HID);
        const uint4* wp = (const uint4*)Woutpk;
        float a = bo_reg;
        for (int w4 = 0; w4 < 32; ++w4) {
            uint4 wv = wp[w4 * 64 + o];
            uint4 hv = hrow[w4];
            a = dot2(wv.x, hv.x, a); a = dot2(wv.y, hv.y, a);
            a = dot2(wv.z, hv.z, a); a = dot2(wv.w, hv.w, a);
        }
        outp[(size_t)t * OUT_DIM + o] = a;
        ring[(t % DELAY) * 64 + o] = f16bits(a);
    };

#pragma unroll 1
    for (int ch = 0; ch < NCH; ++ch) {
        const int t0 = ch * CH;
        if (ch > 0) out_chunk(t0 - CH);
        __syncthreads();

        // ---- stage x|fb rows (8 rows x 64 u32) as f16 pairs ----
        {
            int row = tid >> 6, p = tid & 63;
            int t = t0 + row;
            u32 v;
            if (p < 32) {
                float2 x2 = *(const float2*)(xin + (size_t)t * IN_DIM + 2 * p);
                v = pack2(x2.x, x2.y);
            } else {
                int src = t - DELAY;
                if (src >= 0) {
                    int d = 2 * (p - 32);
                    int sl = src % DELAY;
                    v = (u32)ring[sl * 64 + d] | ((u32)ring[sl * 64 + d + 1] << 16);
                } else v = 0u;
            }
            xfst[row * 68 + p] = v;
        }
        __syncthreads();

        // ---- chunk: cb[tl][g'] = bias + x@Wx^T + fb@Wfb^T (dot2, 2 gates/thr)
        {
            float accA[8], accB[8];
#pragma unroll
            for (int i = 0; i < 8; ++i) { accA[i] = 0.f; accB[i] = 0.f; }
            const uint4* bA = Bpk4 + tid;
            const uint4* bB = Bpk4 + 16 * 512 + tid;
#pragma unroll 2
            for (int kb = 0; kb < 16; ++kb) {
                uint4 wA = bA[kb * 512];
                uint4 wB = bB[kb * 512];
#pragma unroll
                for (int tl = 0; tl < 8; ++tl) {
                    uint4 xv = *(const uint4*)(xfst + tl * 68 + kb * 4);
                    accA[tl] = dot2(wA.x, xv.x, accA[tl]);
                    accA[tl] = dot2(wA.y, xv.y, accA[tl]);
                    accA[tl] = dot2(wA.z, xv.z, accA[tl]);
                    accA[tl] = dot2(wA.w, xv.w, accA[tl]);
                    accB[tl] = dot2(wB.x, xv.x, accB[tl]);
                    accB[tl] = dot2(wB.y, xv.y, accB[tl]);
                    accB[tl] = dot2(wB.z, xv.z, accB[tl]);
                    accB[tl] = dot2(wB.w, xv.w, accB[tl]);
                }
            }
            float2 bs = *(const float2*)(bsum_g + 2 * tid);
#pragma unroll
            for (int tl = 0; tl < 8; ++tl)
                cb32[tl * 512 + tid] = pack2(accA[tl] + bs.x, accB[tl] + bs.y);
        }
        __syncthreads();

        // ---- 8 serial steps ----
#pragma unroll 1
        for (int tl = 0; tl < CH; ++tl) {
            const int t = t0 + tl;
            const u32* hrow = (const u32*)hh + ((t + 1) & 1) * 128 + kq * 32;

#pragma unroll
            for (int half = 0; half < 2; ++half) {
                // glob W_hh tail prefetch (pairs 28..31, one uint4 per gate)
                const uint4* wgp = WgR4 + (half * 4) * 512 + tid;
                uint4 wga = wgp[0];
                uint4 wgb = wgp[512];
                uint4 wgc = wgp[1024];
                uint4 wgd = wgp[1536];

                float acc[4];
                if (kq == 0) {
                    uint2 cv = *(const uint2*)(cb32 + tl * 512 + gl * 4 + half * 2);
                    acc[0] = lo16(cv.x); acc[1] = hi16(cv.x);
                    acc[2] = lo16(cv.y); acc[3] = hi16(cv.y);
                } else {
                    acc[0] = acc[1] = acc[2] = acc[3] = 0.f;
                }
#pragma unroll
                for (int i = 0; i < 6; ++i) {
                    uint4 hv = *(const uint4*)(hrow + 4 * i);
#pragma unroll
                    for (int j = 0; j < 4; ++j) {
                        const int g = half * 4 + j;
                        acc[j] = dot2(wreg[g][4 * i + 0], hv.x, acc[j]);
                        acc[j] = dot2(wreg[g][4 * i + 1], hv.y, acc[j]);
                        acc[j] = dot2(wreg[g][4 * i + 2], hv.z, acc[j]);
                        acc[j] = dot2(wreg[g][4 * i + 3], hv.w, acc[j]);
                    }
                }
                {   // i = 6: pairs 24,25 regs + 26,27 LDS
                    uint4 hv = *(const uint4*)(hrow + 24);
#pragma unroll
                    for (int j = 0; j < 4; ++j) {
                        const int g = half * 4 + j;
                        uint2 lw = *(const uint2*)(ldsw + (g * 512 + tid) * 2);
                        acc[j] = dot2(wreg[g][24], hv.x, acc[j]);
                        acc[j] = dot2(wreg[g][25], hv.y, acc[j]);
                        acc[j] = dot2(lw.x, hv.z, acc[j]);
                        acc[j] = dot2(lw.y, hv.w, acc[j]);
                    }
                }
                {   // i = 7: pairs 28..31 from global prefetch
                    uint4 hv = *(const uint4*)(hrow + 28);
                    acc[0] = dot2(wga.x, hv.x, acc[0]);
                    acc[0] = dot2(wga.y, hv.y, acc[0]);
                    acc[0] = dot2(wga.z, hv.z, acc[0]);
                    acc[0] = dot2(wga.w, hv.w, acc[0]);
                    acc[1] = dot2(wgb.x, hv.x, acc[1]);
                    acc[1] = dot2(wgb.y, hv.y, acc[1]);
                    acc[1] = dot2(wgb.z, hv.z, acc[1]);
                    acc[1] = dot2(wgb.w, hv.w, acc[1]);
                    acc[2] = dot2(wgc.x, hv.x, acc[2]);
                    acc[2] = dot2(wgc.y, hv.y, acc[2]);
                    acc[2] = dot2(wgc.z, hv.z, acc[2]);
                    acc[2] = dot2(wgc.w, hv.w, acc[2]);
                    acc[3] = dot2(wgd.x, hv.x, acc[3]);
                    acc[3] = dot2(wgd.y, hv.y, acc[3]);
                    acc[3] = dot2(wgd.z, hv.z, acc[3]);
                    acc[3] = dot2(wgd.w, hv.w, acc[3]);
                }
                uint2 pw;
                pw.x = pack2(acc[0], acc[1]);
                pw.y = pack2(acc[2], acc[3]);
                *(uint2*)(part + kq * G4 + gl * 8 + half * 4) = pw;
            }
            __syncthreads();

            if (tid < 256) {
                float s0 = 0.f, s1 = 0.f, s2 = 0.f, s3 = 0.f;
#pragma unroll
                for (int k = 0; k < 4; ++k) {
                    uint2 rd = *(const uint2*)(part + k * G4 + tid * 4);
                    s0 += lo16(rd.x); s1 += hi16(rd.x);
                    s2 += lo16(rd.y); s3 += hi16(rd.y);
                }
                // permuted order: ty 0=i, 1=f, 2=g, 3=o
                c_state = sigm(s1) * c_state + sigm(s0) * tanh_f(s2);
                float hval = sigm(s3) * tanh_f(c_state);
                unsigned short hb = f16bits(hval);
                hh[(t & 1) * HID + tid] = hb;
                hg[(t & 15) * HID + tid] = hb;
            }
            __syncthreads();
        }
    }
    out_chunk(TSTEPS - CH);
}

extern "C" void kernel_launch(void* const* d_in, const int* in_sizes, int n_in,
                              void* d_out, int out_size, void* d_ws, size_t ws_size,
                              hipStream_t stream)
{
    (void)in_sizes; (void)n_in; (void)out_size;
    const float* input = (const float*)d_in[0];
    const float* Wx    = (const float*)d_in[1];
    const float* Wfb   = (const float*)d_in[2];
    const float* Whh   = (const float*)d_in[3];
    const float* bih   = (const float*)d_in[4];
    const float* bhh   = (const float*)d_in[5];
    const float* Wo    = (const float*)d_in[6];
    const float* bog   = (const float*)d_in[7];
    float* out = (float*)d_out;

    if (ws_size < (size_t)WS_NEED) return;

    uint4* Bpk4   = (uint4*)((char*)d_ws + WS_BPK);
    uint4* WgR4   = (uint4*)((char*)d_ws + WS_WGR);
    u32*   Woutpk = (u32*)((char*)d_ws + WS_WOUT);
    float* bsum_g = (float*)((char*)d_ws + WS_BSUM);
    unsigned short* hg = (unsigned short*)((char*)d_ws + WS_HG);

    prepack<<<dim3(116), dim3(256), 0, stream>>>(
        Wx, Wfb, Whh, Wo, bih, bhh, Bpk4, WgR4, Woutpk, bsum_g);
    lstm_persist<<<dim3(BATCH), dim3(NTHR), SMEM_BYTES, stream>>>(
        input, Whh, bog, Bpk4, WgR4, Woutpk, bsum_g, hg, out);
}

// Round 4
// 6804.430 us; speedup vs baseline: 1.7057x; 1.0655x over previous
//
#include <hip/hip_runtime.h>

// Delayed-feedback LSTM, persistent kernel: 256 WGs (1 batch elem/CU), 512 thr.
// W_hh (512 KB f16) must live in the register file: 8 waves x 256 VGPR x 64
// lanes x 4B = 512 KB -> ~250 VGPR/thread is structural. r2/r3 showed the
// compiler pins 128 VGPR under __launch_bounds__(512,2) -> wreg spilled ->
// L3-bound. Fix: amdgpu_waves_per_eu(2,2) to force the 256-VGPR budget.
// Serial h-matvec: kq = tid>>7 (k-quarter), 8 gates/thread, k-halves so h is
// read once/step (8 ds_read_b128). Per gate-quarter (32 f16 pairs): 26 in
// VGPRs, 2 in LDS, 4 streamed from global (L2/L3-hot, shared by all WGs).
// Chunk phase (CH=8): x|fb gate matvec via dot2, weights streamed once/chunk.

#define BATCH   256
#define TSTEPS  1024
#define IN_DIM  64
#define HID     256
#define G4      1024
#define OUT_DIM 64
#define DELAY   20
#define CH      8
#define NCH     (TSTEPS / CH)
#define NTHR    512
#define REGP    26              // f16 pairs per gate in registers

typedef unsigned int u32;
typedef _Float16 half2_t __attribute__((ext_vector_type(2)));

union H2U { u32 u; half2_t h; };
union H1U { unsigned short s; _Float16 h; };

__device__ __forceinline__ u32 pack2(float a, float b) {
    H2U x; x.h = half2_t{(_Float16)a, (_Float16)b}; return x.u;
}
__device__ __forceinline__ unsigned short f16bits(float a) {
    H1U x; x.h = (_Float16)a; return x.s;
}
__device__ __forceinline__ float lo16(u32 u) {
    H1U x; x.s = (unsigned short)(u & 0xffffu); return (float)x.h;
}
__device__ __forceinline__ float hi16(u32 u) {
    H1U x; x.s = (unsigned short)(u >> 16); return (float)x.h;
}
__device__ __forceinline__ float dot2(u32 w, u32 h, float acc) {
    H2U a; a.u = w; H2U b; b.u = h;
    return __builtin_amdgcn_fdot2(a.h, b.h, acc, false);
}
__device__ __forceinline__ float sigm(float x) {
    float e = __expf(-fabsf(x));
    float p = 1.f / (1.f + e);
    return x >= 0.f ? p : 1.f - p;
}
__device__ __forceinline__ float tanh_f(float x) {
    float e = __expf(-2.f * fabsf(x));
    float r = (1.f - e) / (1.f + e);
    return x >= 0.f ? r : -r;
}

// LDS layout (bytes), total 63104 <= 65536 (no attribute needed)
#define OFF_LDSW  0        // uint2 [8 q][512 tid]      32768  (W_hh pairs 26,27)
#define OFF_CB    32768    // u32   [8 tl][512]         16384  (2 gates/u32, f16)
#define OFF_PART  49152    // ushort[4 kq][1024]         8192
#define OFF_HH    57344    // ushort[2][256]             1024
#define OFF_RING  58368    // ushort[20][64]             2560
#define OFF_XF    60928    // u32   [8][68]              2176
#define SMEM_BYTES 63104

// ws layout (bytes)
#define WS_BPK    0                    // 262144: chunk Wx|Wfb packed (uint4)
#define WS_WGR    262144               // 65536 : serial W_hh tail pairs 28..31
#define WS_WOUT   327680               // 32768 : packed Wout (u32)
#define WS_BSUM   360448               // 4096  : bias sums (float, permuted)
#define WS_HG     364544               // 2097152: h history [256 b][16][256] f16
#define WS_NEED   (364544 + 2097152)

// permuted gate g' = u*4 + ty  ->  original row ty*256 + u  (ty: 0=i,1=f,2=g,3=o)
__device__ __forceinline__ int orig_row(int gp) {
    return (gp & 3) * 256 + (gp >> 2);
}

__global__ void prepack(const float* __restrict__ Wx,
                        const float* __restrict__ Wfb,
                        const float* __restrict__ Whh,
                        const float* __restrict__ Wout,
                        const float* __restrict__ bih,
                        const float* __restrict__ bhh,
                        uint4* __restrict__ Bpk4,
                        uint4* __restrict__ WgR4,
                        u32* __restrict__ Woutpk,
                        float* __restrict__ bsum_g)
{
    int id = blockIdx.x * 256 + threadIdx.x;
    if (id < 16384) {
        // Bpk4[(j*16+kb)*512 + t]: gate g'=2t+j, K=128 (x|fb), k = kb*8..kb*8+7
        int t = id & 511, rest = id >> 9;
        int kb = rest & 15, j = rest >> 4;
        int r = orig_row(2 * t + j);
        int k0 = kb * 8;
        const float* src = (k0 < 64) ? (Wx + (size_t)r * 64 + k0)
                                     : (Wfb + (size_t)r * 64 + (k0 - 64));
        uint4 v;
        v.x = pack2(src[0], src[1]); v.y = pack2(src[2], src[3]);
        v.z = pack2(src[4], src[5]); v.w = pack2(src[6], src[7]);
        Bpk4[id] = v;
    } else if (id < 16384 + 4096) {
        // WgR4[q*512 + tid]: gate g'=(tid&127)*8+q, quarter kq=tid>>7, k 56..63
        int s = id - 16384;
        int tt = s & 511, q = s >> 9;
        int kq = tt >> 7, gl = tt & 127;
        int r = orig_row(gl * 8 + q);
        const float* w = Whh + (size_t)r * HID + kq * 64 + 56;
        uint4 v;
        v.x = pack2(w[0], w[1]); v.y = pack2(w[2], w[3]);
        v.z = pack2(w[4], w[5]); v.w = pack2(w[6], w[7]);
        WgR4[s] = v;
    } else if (id < 16384 + 4096 + 8192) {
        int s = id - 20480;                 // (w4*64+o)*4+c
        int c = s & 3, o = (s >> 2) & 63, w4 = s >> 8;
        int kp = w4 * 4 + c;
        Woutpk[s] = pack2(Wout[o * HID + 2 * kp], Wout[o * HID + 2 * kp + 1]);
    } else if (id < 16384 + 4096 + 8192 + 1024) {
        int g = id - 28672;
        int r = orig_row(g);
        bsum_g[g] = bih[r] + bhh[r];
    }
}

__global__ __launch_bounds__(NTHR) __attribute__((amdgpu_waves_per_eu(2, 2)))
void lstm_persist(const float* __restrict__ input,
                  const float* __restrict__ Whh,
                  const float* __restrict__ bout_g,
                  const uint4* __restrict__ Bpk4,
                  const uint4* __restrict__ WgR4,
                  const u32* __restrict__ Woutpk,
                  const float* __restrict__ bsum_g,
                  unsigned short* __restrict__ hg_all,
                  float* __restrict__ out)
{
    extern __shared__ char smem[];
    u32*            ldsw  = (u32*)(smem + OFF_LDSW);
    u32*            cb32  = (u32*)(smem + OFF_CB);
    unsigned short* part  = (unsigned short*)(smem + OFF_PART);
    unsigned short* hh    = (unsigned short*)(smem + OFF_HH);
    unsigned short* ring  = (unsigned short*)(smem + OFF_RING);
    u32*            xfst  = (u32*)(smem + OFF_XF);

    const int tid = threadIdx.x;
    const int b   = blockIdx.x;
    const int kq  = tid >> 7;         // wave-uniform k-quarter
    const int gl  = tid & 127;        // gate block: permuted gates gl*8..gl*8+7

    const float* xin  = input + (size_t)b * TSTEPS * IN_DIM;
    float*       outp = out + (size_t)b * TSTEPS * OUT_DIM;
    unsigned short* hg = hg_all + (size_t)b * (16 * HID);
    const float bo_reg = bout_g[tid & 63];

    // ---- init: W_hh pairs 0..25 of k-quarter into regs, 26..27 into LDS ----
    u32 wreg[8][REGP];
#pragma unroll
    for (int q = 0; q < 8; ++q) {
        const int r = orig_row(gl * 8 + q);
        const float* wrow = Whh + (size_t)r * HID + kq * 64;
#pragma unroll
        for (int p = 0; p < REGP; ++p) {
            float2 w2 = *(const float2*)(wrow + 2 * p);
            wreg[q][p] = pack2(w2.x, w2.y);
        }
        float2 wa = *(const float2*)(wrow + 52);
        float2 wb = *(const float2*)(wrow + 54);
        u32 base = (q * 512 + tid) * 2;
        ldsw[base]     = pack2(wa.x, wa.y);
        ldsw[base + 1] = pack2(wb.x, wb.y);
    }
    if (tid < 256) { hh[tid] = 0; hh[256 + tid] = 0; }
    __syncthreads();

    float c_state = 0.f;

    // out matvec for steps [tbase, tbase+8): one (t,o) per thread
    auto out_chunk = [&](int tbase) {
        const int lt = tid >> 6, o = tid & 63;
        const int t = tbase + lt;
        const uint4* hrow = (const uint4*)(hg + (t & 15) * HID);
        const uint4* wp = (const uint4*)Woutpk;
        float a = bo_reg;
        for (int w4 = 0; w4 < 32; ++w4) {
            uint4 wv = wp[w4 * 64 + o];
            uint4 hv = hrow[w4];
            a = dot2(wv.x, hv.x, a); a = dot2(wv.y, hv.y, a);
            a = dot2(wv.z, hv.z, a); a = dot2(wv.w, hv.w, a);
        }
        outp[(size_t)t * OUT_DIM + o] = a;
        ring[(t % DELAY) * 64 + o] = f16bits(a);
    };

#pragma unroll 1
    for (int ch = 0; ch < NCH; ++ch) {
        const int t0 = ch * CH;
        if (ch > 0) out_chunk(t0 - CH);
        __syncthreads();

        // ---- stage x|fb rows (8 rows x 64 u32) as f16 pairs ----
        {
            int row = tid >> 6, p = tid & 63;
            int t = t0 + row;
            u32 v;
            if (p < 32) {
                float2 x2 = *(const float2*)(xin + (size_t)t * IN_DIM + 2 * p);
                v = pack2(x2.x, x2.y);
            } else {
                int src = t - DELAY;
                if (src >= 0) {
                    int d = 2 * (p - 32);
                    int sl = src % DELAY;
                    v = (u32)ring[sl * 64 + d] | ((u32)ring[sl * 64 + d + 1] << 16);
                } else v = 0u;
            }
            xfst[row * 68 + p] = v;
        }
        __syncthreads();

        // ---- chunk: cb[tl][g'] = bias + x@Wx^T + fb@Wfb^T (dot2, 2 gates/thr)
        {
            float accA[8], accB[8];
#pragma unroll
            for (int i = 0; i < 8; ++i) { accA[i] = 0.f; accB[i] = 0.f; }
            const uint4* bA = Bpk4 + tid;
            const uint4* bB = Bpk4 + 16 * 512 + tid;
#pragma unroll 1
            for (int kb = 0; kb < 16; ++kb) {
                uint4 wA = bA[kb * 512];
                uint4 wB = bB[kb * 512];
#pragma unroll
                for (int tl = 0; tl < 8; ++tl) {
                    uint4 xv = *(const uint4*)(xfst + tl * 68 + kb * 4);
                    accA[tl] = dot2(wA.x, xv.x, accA[tl]);
                    accA[tl] = dot2(wA.y, xv.y, accA[tl]);
                    accA[tl] = dot2(wA.z, xv.z, accA[tl]);
                    accA[tl] = dot2(wA.w, xv.w, accA[tl]);
                    accB[tl] = dot2(wB.x, xv.x, accB[tl]);
                    accB[tl] = dot2(wB.y, xv.y, accB[tl]);
                    accB[tl] = dot2(wB.z, xv.z, accB[tl]);
                    accB[tl] = dot2(wB.w, xv.w, accB[tl]);
                }
            }
            float2 bs = *(const float2*)(bsum_g + 2 * tid);
#pragma unroll
            for (int tl = 0; tl < 8; ++tl)
                cb32[tl * 512 + tid] = pack2(accA[tl] + bs.x, accB[tl] + bs.y);
        }
        __syncthreads();

        // ---- 8 serial steps (k-halves: h read once per step) ----
#pragma unroll 1
        for (int tl = 0; tl < CH; ++tl) {
            const int t = t0 + tl;
            const u32* hrow = (const u32*)hh + ((t + 1) & 1) * 128 + kq * 32;

            float acc[8];
            if (kq == 0) {
                uint4 cv = *(const uint4*)(cb32 + tl * 512 + gl * 4);
                acc[0] = lo16(cv.x); acc[1] = hi16(cv.x);
                acc[2] = lo16(cv.y); acc[3] = hi16(cv.y);
                acc[4] = lo16(cv.z); acc[5] = hi16(cv.z);
                acc[6] = lo16(cv.w); acc[7] = hi16(cv.w);
            } else {
#pragma unroll
                for (int q = 0; q < 8; ++q) acc[q] = 0.f;
            }
            {   // k-half 0: pairs 0..15 (all registers)
                uint4 h0 = *(const uint4*)(hrow + 0);
                uint4 h1 = *(const uint4*)(hrow + 4);
                uint4 h2 = *(const uint4*)(hrow + 8);
                uint4 h3 = *(const uint4*)(hrow + 12);
#pragma unroll
                for (int q = 0; q < 8; ++q) {
                    acc[q] = dot2(wreg[q][0],  h0.x, acc[q]);
                    acc[q] = dot2(wreg[q][1],  h0.y, acc[q]);
                    acc[q] = dot2(wreg[q][2],  h0.z, acc[q]);
                    acc[q] = dot2(wreg[q][3],  h0.w, acc[q]);
                    acc[q] = dot2(wreg[q][4],  h1.x, acc[q]);
                    acc[q] = dot2(wreg[q][5],  h1.y, acc[q]);
                    acc[q] = dot2(wreg[q][6],  h1.z, acc[q]);
                    acc[q] = dot2(wreg[q][7],  h1.w, acc[q]);
                    acc[q] = dot2(wreg[q][8],  h2.x, acc[q]);
                    acc[q] = dot2(wreg[q][9],  h2.y, acc[q]);
                    acc[q] = dot2(wreg[q][10], h2.z, acc[q]);
                    acc[q] = dot2(wreg[q][11], h2.w, acc[q]);
                    acc[q] = dot2(wreg[q][12], h3.x, acc[q]);
                    acc[q] = dot2(wreg[q][13], h3.y, acc[q]);
                    acc[q] = dot2(wreg[q][14], h3.z, acc[q]);
                    acc[q] = dot2(wreg[q][15], h3.w, acc[q]);
                }
            }
            {   // k-half 1: pairs 16..25 regs, 26..27 LDS, 28..31 global
                uint4 h4 = *(const uint4*)(hrow + 16);
                uint4 h5 = *(const uint4*)(hrow + 20);
                uint4 h6 = *(const uint4*)(hrow + 24);
                uint4 h7 = *(const uint4*)(hrow + 28);
#pragma unroll
                for (int grp = 0; grp < 2; ++grp) {
                    const uint4* wgp = WgR4 + (grp * 4) * 512 + tid;
                    uint4 wg0 = wgp[0];
                    uint4 wg1 = wgp[512];
                    uint4 wg2 = wgp[1024];
                    uint4 wg3 = wgp[1536];
#pragma unroll
                    for (int j = 0; j < 4; ++j) {
                        const int q = grp * 4 + j;
                        acc[q] = dot2(wreg[q][16], h4.x, acc[q]);
                        acc[q] = dot2(wreg[q][17], h4.y, acc[q]);
                        acc[q] = dot2(wreg[q][18], h4.z, acc[q]);
                        acc[q] = dot2(wreg[q][19], h4.w, acc[q]);
                        acc[q] = dot2(wreg[q][20], h5.x, acc[q]);
                        acc[q] = dot2(wreg[q][21], h5.y, acc[q]);
                        acc[q] = dot2(wreg[q][22], h5.z, acc[q]);
                        acc[q] = dot2(wreg[q][23], h5.w, acc[q]);
                        acc[q] = dot2(wreg[q][24], h6.x, acc[q]);
                        acc[q] = dot2(wreg[q][25], h6.y, acc[q]);
                        uint2 lw = *(const uint2*)(ldsw + (q * 512 + tid) * 2);
                        acc[q] = dot2(lw.x, h6.z, acc[q]);
                        acc[q] = dot2(lw.y, h6.w, acc[q]);
                        uint4 wg = (j == 0) ? wg0 : (j == 1) ? wg1 : (j == 2) ? wg2 : wg3;
                        acc[q] = dot2(wg.x, h7.x, acc[q]);
                        acc[q] = dot2(wg.y, h7.y, acc[q]);
                        acc[q] = dot2(wg.z, h7.z, acc[q]);
                        acc[q] = dot2(wg.w, h7.w, acc[q]);
                    }
                }
            }
            {   // one ds_write_b128 of the 8-gate partial (f16)
                uint4 pw;
                pw.x = pack2(acc[0], acc[1]); pw.y = pack2(acc[2], acc[3]);
                pw.z = pack2(acc[4], acc[5]); pw.w = pack2(acc[6], acc[7]);
                *(uint4*)(part + kq * G4 + gl * 8) = pw;
            }
            __syncthreads();

            if (tid < 256) {
                float s0 = 0.f, s1 = 0.f, s2 = 0.f, s3 = 0.f;
#pragma unroll
                for (int k = 0; k < 4; ++k) {
                    uint2 rd = *(const uint2*)(part + k * G4 + tid * 4);
                    s0 += lo16(rd.x); s1 += hi16(rd.x);
                    s2 += lo16(rd.y); s3 += hi16(rd.y);
                }
                // permuted order: ty 0=i, 1=f, 2=g, 3=o
                c_state = sigm(s1) * c_state + sigm(s0) * tanh_f(s2);
                float hval = sigm(s3) * tanh_f(c_state);
                unsigned short hb = f16bits(hval);
                hh[(t & 1) * HID + tid] = hb;
                hg[(t & 15) * HID + tid] = hb;
            }
            __syncthreads();
        }
    }
    out_chunk(TSTEPS - CH);
}

extern "C" void kernel_launch(void* const* d_in, const int* in_sizes, int n_in,
                              void* d_out, int out_size, void* d_ws, size_t ws_size,
                              hipStream_t stream)
{
    (void)in_sizes; (void)n_in; (void)out_size;
    const float* input = (const float*)d_in[0];
    const float* Wx    = (const float*)d_in[1];
    const float* Wfb   = (const float*)d_in[2];
    const float* Whh   = (const float*)d_in[3];
    const float* bih   = (const float*)d_in[4];
    const float* bhh   = (const float*)d_in[5];
    const float* Wo    = (const float*)d_in[6];
    const float* bog   = (const float*)d_in[7];
    float* out = (float*)d_out;

    if (ws_size < (size_t)WS_NEED) return;

    uint4* Bpk4   = (uint4*)((char*)d_ws + WS_BPK);
    uint4* WgR4   = (uint4*)((char*)d_ws + WS_WGR);
    u32*   Woutpk = (u32*)((char*)d_ws + WS_WOUT);
    float* bsum_g = (float*)((char*)d_ws + WS_BSUM);
    unsigned short* hg = (unsigned short*)((char*)d_ws + WS_HG);

    prepack<<<dim3(116), dim3(256), 0, stream>>>(
        Wx, Wfb, Whh, Wo, bih, bhh, Bpk4, WgR4, Woutpk, bsum_g);
    lstm_persist<<<dim3(BATCH), dim3(NTHR), SMEM_BYTES, stream>>>(
        input, Whh, bog, Bpk4, WgR4, Woutpk, bsum_g, hg, out);
}